// Round 2
// baseline (2605.515 us; speedup 1.0000x reference)
//
#include <hip/hip_runtime.h>

#define HASH_MASK ((1u << 19) - 1u)

typedef float f32x2 __attribute__((ext_vector_type(2)));

// Level offsets: l0:0, l1:4913, l2:40850, l3:315475, then +524288/level.
__device__ __forceinline__ unsigned level_offset(int l) {
    unsigned lo = (l == 0) ? 0u : ((l == 1) ? 4913u : 40850u);
    unsigned hi = 315475u + (unsigned)(l - 3) * 524288u;
    return (l >= 3) ? hi : lo;
}

__global__ __launch_bounds__(256) void hashgrid4d_kernel(
    const float* __restrict__ x, const float* __restrict__ t,
    const float* __restrict__ e0, const float* __restrict__ e1,
    const float* __restrict__ e2, const float* __restrict__ e3,
    float* __restrict__ out, int B)
{
    const int gid   = blockIdx.x * blockDim.x + threadIdx.x;
    const int point = gid >> 6;          // one wave (64 lanes) per point
    if (point >= B) return;
    const int lane = threadIdx.x & 63;
    const int l = lane & 15;             // level
    const int e = lane >> 4;             // encode: 0=static,1=xyt,2=xzt,3=yzt

    // Per-point coordinates (wave-uniform loads, L1 broadcast)
    const float x0 = x[point * 3 + 0];
    const float x1 = x[point * 3 + 1];
    const float x2 = x[point * 3 + 2];
    const float tt = t[point];

    // encode->coordinate selection:
    // e0:(x0,x1,x2) e1:(x0,x1,t) e2:(x0,x2,t) e3:(x1,x2,t)
    const float c0 = (e == 3) ? x1 : x0;
    const float c1 = (e <= 1) ? x1 : x2;
    const float c2 = (e == 0) ? x2 : tt;

    const float* tab = (e == 0) ? e0 : ((e == 1) ? e1 : ((e == 2) ? e2 : e3));

    const int res = 16 << l;
    const float resf = (float)res;

    // pos / floor / frac exactly as reference (all f32)
    const float p0 = c0 * resf, p1 = c1 * resf, p2 = c2 * resf;
    const float fl0 = floorf(p0), fl1 = floorf(p1), fl2 = floorf(p2);
    const float f0 = p0 - fl0, f1 = p1 - fl1, f2 = p2 - fl2;
    const unsigned g0 = (unsigned)min(max((int)fl0, 0), res - 1);
    const unsigned g1 = (unsigned)min(max((int)fl1, 0), res - 1);
    const unsigned g2 = (unsigned)min(max((int)fl2, 0), res - 1);

    const bool dense = (l < 3);
    const unsigned offs = level_offset(l);

    // Dense index precompute: base + bx + by*r1 + bz*r1^2
    const unsigned r1 = (unsigned)(res + 1);
    const unsigned r1sq = r1 * r1;
    const unsigned d_base = g0 + g1 * r1 + g2 * r1sq;

    // Hash precompute: idx = (g0+bx) ^ ((g1+by)*P1) ^ ((g2+bz)*P2), mod 2^19
    const unsigned h1a = g1 * 2654435761u;
    const unsigned h1b = (g1 + 1u) * 2654435761u;
    const unsigned h2a = g2 * 805459861u;
    const unsigned h2b = (g2 + 1u) * 805459861u;

    const float omf0 = 1.0f - f0, omf1 = 1.0f - f1, omf2 = 1.0f - f2;

    float acc0 = 0.0f, acc1 = 0.0f;
#pragma unroll
    for (int c = 0; c < 8; ++c) {
        const int bx = c & 1, by = (c >> 1) & 1, bz = c >> 2;
        const float w = (bx ? f0 : omf0) * (by ? f1 : omf1) * (bz ? f2 : omf2);
        const unsigned di = d_base + (bx ? 1u : 0u) + (by ? r1 : 0u) + (bz ? r1sq : 0u);
        const unsigned hi = (((g0 + (unsigned)bx) ^ (by ? h1b : h1a) ^ (bz ? h2b : h2a)) & HASH_MASK);
        const unsigned idx = dense ? di : hi;
        const f32x2 v = *reinterpret_cast<const f32x2*>(tab + 2u * (offs + idx));
        acc0 = fmaf(w, v.x, acc0);
        acc1 = fmaf(w, v.y, acc1);
    }

    // Output col = e*32 + l*2 + ch = lane*2 + ch ; one wave writes a full 512B row.
    f32x2 r; r.x = acc0; r.y = acc1;
    __builtin_nontemporal_store(r, reinterpret_cast<f32x2*>(out + (size_t)point * 128 + lane * 2));
}

extern "C" void kernel_launch(void* const* d_in, const int* in_sizes, int n_in,
                              void* d_out, int out_size, void* d_ws, size_t ws_size,
                              hipStream_t stream) {
    const float* x  = (const float*)d_in[0];
    const float* t  = (const float*)d_in[1];
    const float* es = (const float*)d_in[2];
    const float* e1 = (const float*)d_in[3];
    const float* e2 = (const float*)d_in[4];
    const float* e3 = (const float*)d_in[5];
    float* out = (float*)d_out;
    const int B = in_sizes[0] / 3;

    const int threads = 256;                 // 4 waves = 4 points per block
    const long long total = (long long)B * 64;
    const int blocks = (int)((total + threads - 1) / threads);
    hashgrid4d_kernel<<<blocks, threads, 0, stream>>>(x, t, es, e1, e2, e3, out, B);
}

// Round 3
// 2333.552 us; speedup vs baseline: 1.1165x; 1.1165x over previous
//
#include <hip/hip_runtime.h>

#define HASH_MASK ((1u << 19) - 1u)
#define TABLE_SIZE 7131219u
#define SCALE 1048576.0f          // 2^20 (exact)
#define INV_SCALE 9.5367431640625e-07f  // 2^-20 (exact)

typedef float    f32x2 __attribute__((ext_vector_type(2)));
typedef _Float16 f16x2 __attribute__((ext_vector_type(2)));

// Level offsets: l0:0, l1:4913, l2:40850, l3:315475, then +524288/level.
__device__ __forceinline__ unsigned level_offset(int l) {
    unsigned lo = (l == 0) ? 0u : ((l == 1) ? 4913u : 40850u);
    unsigned hi = 315475u + (unsigned)(l - 3) * 524288u;
    return (l >= 3) ? hi : lo;
}

// Pre-pass: f32 tables -> fp16 (scaled by 2^20) in workspace. Runs every call.
__global__ __launch_bounds__(256) void convert_tables_kernel(
    const float* __restrict__ e0, const float* __restrict__ e1,
    const float* __restrict__ e2, const float* __restrict__ e3,
    f16x2* __restrict__ ws)
{
    const unsigned i = blockIdx.x * blockDim.x + threadIdx.x;
    if (i >= TABLE_SIZE) return;
    const float* src = (blockIdx.y == 0) ? e0 : ((blockIdx.y == 1) ? e1
                     : ((blockIdx.y == 2) ? e2 : e3));
    // nontemporal: don't let the dying f32 copies evict the fp16 set from L3
    const float v0 = __builtin_nontemporal_load(src + 2u * i);
    const float v1 = __builtin_nontemporal_load(src + 2u * i + 1u);
    f16x2 h;
    h.x = (_Float16)(v0 * SCALE);
    h.y = (_Float16)(v1 * SCALE);
    ws[blockIdx.y * TABLE_SIZE + i] = h;
}

template <typename VEC, typename TAB>
__device__ __forceinline__ void hashgrid_body(
    const float* __restrict__ x, const float* __restrict__ t,
    TAB tab_sel, float* __restrict__ out, int B, float out_scale)
{
    const int gid   = blockIdx.x * blockDim.x + threadIdx.x;
    const int point = gid >> 6;          // one wave (64 lanes) per point
    if (point >= B) return;
    const int lane = threadIdx.x & 63;
    const int l = lane & 15;             // level
    const int e = lane >> 4;             // encode: 0=static,1=xyt,2=xzt,3=yzt

    const float x0 = x[point * 3 + 0];
    const float x1 = x[point * 3 + 1];
    const float x2 = x[point * 3 + 2];
    const float tt = t[point];

    // e0:(x0,x1,x2) e1:(x0,x1,t) e2:(x0,x2,t) e3:(x1,x2,t)
    const float c0 = (e == 3) ? x1 : x0;
    const float c1 = (e <= 1) ? x1 : x2;
    const float c2 = (e == 0) ? x2 : tt;

    const int res = 16 << l;
    const float resf = (float)res;

    const float p0 = c0 * resf, p1 = c1 * resf, p2 = c2 * resf;
    const float fl0 = floorf(p0), fl1 = floorf(p1), fl2 = floorf(p2);
    const float f0 = p0 - fl0, f1 = p1 - fl1, f2 = p2 - fl2;
    const unsigned g0 = (unsigned)min(max((int)fl0, 0), res - 1);
    const unsigned g1 = (unsigned)min(max((int)fl1, 0), res - 1);
    const unsigned g2 = (unsigned)min(max((int)fl2, 0), res - 1);

    const bool dense = (l < 3);
    const unsigned offs = level_offset(l);

    const unsigned r1 = (unsigned)(res + 1);
    const unsigned r1sq = r1 * r1;
    const unsigned d_base = g0 + g1 * r1 + g2 * r1sq;

    const unsigned h1a = g1 * 2654435761u;
    const unsigned h1b = (g1 + 1u) * 2654435761u;
    const unsigned h2a = g2 * 805459861u;
    const unsigned h2b = (g2 + 1u) * 805459861u;

    const float omf0 = 1.0f - f0, omf1 = 1.0f - f1, omf2 = 1.0f - f2;

    float acc0 = 0.0f, acc1 = 0.0f;
#pragma unroll
    for (int c = 0; c < 8; ++c) {
        const int bx = c & 1, by = (c >> 1) & 1, bz = c >> 2;
        const float w = (bx ? f0 : omf0) * (by ? f1 : omf1) * (bz ? f2 : omf2);
        const unsigned di = d_base + (bx ? 1u : 0u) + (by ? r1 : 0u) + (bz ? r1sq : 0u);
        const unsigned hi = (((g0 + (unsigned)bx) ^ (by ? h1b : h1a) ^ (bz ? h2b : h2a)) & HASH_MASK);
        const unsigned idx = dense ? di : hi;
        const VEC v = tab_sel(e, offs + idx);
        acc0 = fmaf(w, (float)v.x, acc0);
        acc1 = fmaf(w, (float)v.y, acc1);
    }

    f32x2 r;
    r.x = acc0 * out_scale;
    r.y = acc1 * out_scale;
    __builtin_nontemporal_store(r, reinterpret_cast<f32x2*>(out + (size_t)point * 128 + lane * 2));
}

__global__ __launch_bounds__(256) void hashgrid4d_f16_kernel(
    const float* __restrict__ x, const float* __restrict__ t,
    const f16x2* __restrict__ ws, float* __restrict__ out, int B)
{
    hashgrid_body<f16x2>(x, t,
        [ws](int e, unsigned idx) -> f16x2 {
            return ws[(unsigned)e * TABLE_SIZE + idx];
        },
        out, B, INV_SCALE);
}

__global__ __launch_bounds__(256) void hashgrid4d_f32_kernel(
    const float* __restrict__ x, const float* __restrict__ t,
    const float* __restrict__ e0, const float* __restrict__ e1,
    const float* __restrict__ e2, const float* __restrict__ e3,
    float* __restrict__ out, int B)
{
    hashgrid_body<f32x2>(x, t,
        [e0, e1, e2, e3](int e, unsigned idx) -> f32x2 {
            const float* tab = (e == 0) ? e0 : ((e == 1) ? e1 : ((e == 2) ? e2 : e3));
            return *reinterpret_cast<const f32x2*>(tab + 2u * idx);
        },
        out, B, 1.0f);
}

extern "C" void kernel_launch(void* const* d_in, const int* in_sizes, int n_in,
                              void* d_out, int out_size, void* d_ws, size_t ws_size,
                              hipStream_t stream) {
    const float* x  = (const float*)d_in[0];
    const float* t  = (const float*)d_in[1];
    const float* e0 = (const float*)d_in[2];
    const float* e1 = (const float*)d_in[3];
    const float* e2 = (const float*)d_in[4];
    const float* e3 = (const float*)d_in[5];
    float* out = (float*)d_out;
    const int B = in_sizes[0] / 3;

    const int threads = 256;                 // 4 waves = 4 points per block
    const long long total = (long long)B * 64;
    const int blocks = (int)((total + threads - 1) / threads);

    const size_t need = (size_t)TABLE_SIZE * 4u * sizeof(f16x2);  // 4 tables x 4 B
    if (ws_size >= need) {
        dim3 cgrid((TABLE_SIZE + 255u) / 256u, 4);
        convert_tables_kernel<<<cgrid, 256, 0, stream>>>(e0, e1, e2, e3, (f16x2*)d_ws);
        hashgrid4d_f16_kernel<<<blocks, threads, 0, stream>>>(x, t, (const f16x2*)d_ws, out, B);
    } else {
        hashgrid4d_f32_kernel<<<blocks, threads, 0, stream>>>(x, t, e0, e1, e2, e3, out, B);
    }
}

// Round 4
// 926.740 us; speedup vs baseline: 2.8115x; 2.5180x over previous
//
#include <hip/hip_runtime.h>

#define HASH_MASK ((1u << 19) - 1u)
#define TABLE_SIZE 7131219u
#define SCALE 1048576.0f               // 2^20 (exact)
#define INV_SCALE 9.5367431640625e-07f // 2^-20 (exact)

typedef float    f32x2 __attribute__((ext_vector_type(2)));
typedef float    f32x4 __attribute__((ext_vector_type(4)));
typedef _Float16 f16x2 __attribute__((ext_vector_type(2)));

// Level offsets: l0:0, l1:4913, l2:40850, l3:315475, then +524288/level.
__device__ __forceinline__ unsigned level_offset(int l) {
    unsigned lo = (l == 0) ? 0u : ((l == 1) ? 4913u : 40850u);
    unsigned hi = 315475u + (unsigned)(l - 3) * 524288u;
    return (l >= 3) ? hi : lo;
}

// ---------------- pre-pass: f32 tables -> fp16 (x 2^20) in ws ----------------
__global__ __launch_bounds__(256) void convert_tables_kernel(
    const float* __restrict__ e0, const float* __restrict__ e1,
    const float* __restrict__ e2, const float* __restrict__ e3,
    f16x2* __restrict__ ws)
{
    const unsigned i = blockIdx.x * blockDim.x + threadIdx.x;
    if (i >= TABLE_SIZE) return;
    const float* src = (blockIdx.y == 0) ? e0 : ((blockIdx.y == 1) ? e1
                     : ((blockIdx.y == 2) ? e2 : e3));
    const float v0 = __builtin_nontemporal_load(src + 2u * i);
    const float v1 = __builtin_nontemporal_load(src + 2u * i + 1u);
    f16x2 h;
    h.x = (_Float16)(v0 * SCALE);
    h.y = (_Float16)(v1 * SCALE);
    ws[blockIdx.y * TABLE_SIZE + i] = h;  // regular store: keep in cache hierarchy
}

// ------------- main pass: one (encode,level) combo per block ----------------
// blockIdx.x = combo * nchunk + chunk  -> dispatch order serializes combos so
// the combo's <=2MB fp16 slice stays L2-resident on every XCD. nchunk %8==0 so
// chunk->XCD striping (blockIdx%8) keeps each XCD's coord stripe L2-resident.
__global__ __launch_bounds__(256) void hg_pass_kernel(
    const float* __restrict__ x, const float* __restrict__ t,
    const f16x2* __restrict__ ws, f32x2* __restrict__ sc,
    int B, int nchunk)
{
    const int combo = blockIdx.x / nchunk;
    const int chunk = blockIdx.x - combo * nchunk;
    const int point = chunk * 256 + threadIdx.x;
    if (point >= B) return;
    const int e = combo >> 4;     // combo = e*16 + l
    const int l = combo & 15;

    const float x0 = x[point * 3 + 0];
    const float x1 = x[point * 3 + 1];
    const float x2 = x[point * 3 + 2];
    const float tt = t[point];
    // e0:(x0,x1,x2) e1:(x0,x1,t) e2:(x0,x2,t) e3:(x1,x2,t)
    const float c0 = (e == 3) ? x1 : x0;
    const float c1 = (e <= 1) ? x1 : x2;
    const float c2 = (e == 0) ? x2 : tt;

    const f16x2* __restrict__ tab = ws + (size_t)e * TABLE_SIZE;

    const int res = 16 << l;
    const float resf = (float)res;
    const float p0 = c0 * resf, p1 = c1 * resf, p2 = c2 * resf;
    const float fl0 = floorf(p0), fl1 = floorf(p1), fl2 = floorf(p2);
    const float f0 = p0 - fl0, f1 = p1 - fl1, f2 = p2 - fl2;
    const unsigned g0 = (unsigned)min(max((int)fl0, 0), res - 1);
    const unsigned g1 = (unsigned)min(max((int)fl1, 0), res - 1);
    const unsigned g2 = (unsigned)min(max((int)fl2, 0), res - 1);

    const bool dense = (l < 3);
    const unsigned offs = level_offset(l);
    const unsigned r1 = (unsigned)(res + 1);
    const unsigned r1sq = r1 * r1;
    const unsigned d_base = g0 + g1 * r1 + g2 * r1sq;
    const unsigned h1a = g1 * 2654435761u, h1b = (g1 + 1u) * 2654435761u;
    const unsigned h2a = g2 * 805459861u,  h2b = (g2 + 1u) * 805459861u;
    const float omf0 = 1.0f - f0, omf1 = 1.0f - f1, omf2 = 1.0f - f2;

    float a0 = 0.0f, a1 = 0.0f;
#pragma unroll
    for (int c = 0; c < 8; ++c) {
        const int bx = c & 1, by = (c >> 1) & 1, bz = c >> 2;
        const float w = (bx ? f0 : omf0) * (by ? f1 : omf1) * (bz ? f2 : omf2);
        const unsigned di = d_base + (bx ? 1u : 0u) + (by ? r1 : 0u) + (bz ? r1sq : 0u);
        const unsigned hi = (((g0 + (unsigned)bx) ^ (by ? h1b : h1a) ^ (bz ? h2b : h2a)) & HASH_MASK);
        const unsigned idx = dense ? di : hi;
        const f16x2 v = tab[offs + idx];
        a0 = fmaf(w, (float)v.x, a0);
        a1 = fmaf(w, (float)v.y, a1);
    }

    // combo-major scratch, coalesced 8B/lane; nontemporal so the write stream
    // doesn't evict the table slice from L2.
    f32x2 r; r.x = a0 * INV_SCALE; r.y = a1 * INV_SCALE;
    __builtin_nontemporal_store(r, &sc[(size_t)combo * (size_t)B + (size_t)point]);
}

// ------------- transpose: sc[64 combos][B points] -> out[B][128] ------------
__global__ __launch_bounds__(256) void transpose_kernel(
    const f32x2* __restrict__ sc, float* __restrict__ out, int B)
{
    __shared__ f32x2 tile[64][65];   // +1 pad: LDS bank spread
    const int pbase = blockIdx.x * 64;
    const int tid = (int)threadIdx.x;

    // read phase: 16 iters x (4 combos x 64 points), 512B coalesced per wave
    const int pr = tid & 63;
    const int gp_r = pbase + pr;
#pragma unroll
    for (int i = 0; i < 16; ++i) {
        const int c = i * 4 + (tid >> 6);
        if (gp_r < B)
            tile[pr][c] = __builtin_nontemporal_load(&sc[(size_t)c * (size_t)B + (size_t)gp_r]);
    }
    __syncthreads();

    // write phase: 8 iters x (8 rows x 512B), 16B/lane coalesced
    const int pw = tid >> 5;         // 0..7 within iter
    const int c2 = (tid & 31) * 2;   // combo pair -> 16B
#pragma unroll
    for (int j = 0; j < 8; ++j) {
        const int p = j * 8 + pw;
        const int gp = pbase + p;
        if (gp < B) {
            const f32x2 v0 = tile[p][c2];
            const f32x2 v1 = tile[p][c2 + 1];
            f32x4 v; v.x = v0.x; v.y = v0.y; v.z = v1.x; v.w = v1.y;
            __builtin_nontemporal_store(v, reinterpret_cast<f32x4*>(out + (size_t)gp * 128 + c2 * 2));
        }
    }
}

// ---------------- fallback: fused fp16 kernel (round-3 version) -------------
__global__ __launch_bounds__(256) void hashgrid4d_f16_kernel(
    const float* __restrict__ x, const float* __restrict__ t,
    const f16x2* __restrict__ ws, float* __restrict__ out, int B)
{
    const int gid   = blockIdx.x * blockDim.x + threadIdx.x;
    const int point = gid >> 6;
    if (point >= B) return;
    const int lane = threadIdx.x & 63;
    const int l = lane & 15;
    const int e = lane >> 4;

    const float x0 = x[point * 3 + 0], x1 = x[point * 3 + 1], x2 = x[point * 3 + 2];
    const float tt = t[point];
    const float c0 = (e == 3) ? x1 : x0;
    const float c1 = (e <= 1) ? x1 : x2;
    const float c2 = (e == 0) ? x2 : tt;
    const f16x2* tab = ws + (size_t)e * TABLE_SIZE;

    const int res = 16 << l;
    const float resf = (float)res;
    const float p0 = c0 * resf, p1 = c1 * resf, p2 = c2 * resf;
    const float fl0 = floorf(p0), fl1 = floorf(p1), fl2 = floorf(p2);
    const float f0 = p0 - fl0, f1 = p1 - fl1, f2 = p2 - fl2;
    const unsigned g0 = (unsigned)min(max((int)fl0, 0), res - 1);
    const unsigned g1 = (unsigned)min(max((int)fl1, 0), res - 1);
    const unsigned g2 = (unsigned)min(max((int)fl2, 0), res - 1);
    const bool dense = (l < 3);
    const unsigned offs = level_offset(l);
    const unsigned r1 = (unsigned)(res + 1), r1sq = r1 * r1;
    const unsigned d_base = g0 + g1 * r1 + g2 * r1sq;
    const unsigned h1a = g1 * 2654435761u, h1b = (g1 + 1u) * 2654435761u;
    const unsigned h2a = g2 * 805459861u,  h2b = (g2 + 1u) * 805459861u;
    const float omf0 = 1.0f - f0, omf1 = 1.0f - f1, omf2 = 1.0f - f2;

    float a0 = 0.0f, a1 = 0.0f;
#pragma unroll
    for (int c = 0; c < 8; ++c) {
        const int bx = c & 1, by = (c >> 1) & 1, bz = c >> 2;
        const float w = (bx ? f0 : omf0) * (by ? f1 : omf1) * (bz ? f2 : omf2);
        const unsigned di = d_base + (bx ? 1u : 0u) + (by ? r1 : 0u) + (bz ? r1sq : 0u);
        const unsigned hi = (((g0 + (unsigned)bx) ^ (by ? h1b : h1a) ^ (bz ? h2b : h2a)) & HASH_MASK);
        const unsigned idx = dense ? di : hi;
        const f16x2 v = tab[offs + idx];
        a0 = fmaf(w, (float)v.x, a0);
        a1 = fmaf(w, (float)v.y, a1);
    }
    f32x2 r; r.x = a0 * INV_SCALE; r.y = a1 * INV_SCALE;
    __builtin_nontemporal_store(r, reinterpret_cast<f32x2*>(out + (size_t)point * 128 + lane * 2));
}

extern "C" void kernel_launch(void* const* d_in, const int* in_sizes, int n_in,
                              void* d_out, int out_size, void* d_ws, size_t ws_size,
                              hipStream_t stream) {
    const float* x  = (const float*)d_in[0];
    const float* t  = (const float*)d_in[1];
    const float* e0 = (const float*)d_in[2];
    const float* e1 = (const float*)d_in[3];
    const float* e2 = (const float*)d_in[4];
    const float* e3 = (const float*)d_in[5];
    float* out = (float*)d_out;
    const int B = in_sizes[0] / 3;

    const size_t tab_bytes = (size_t)TABLE_SIZE * 4u * sizeof(f16x2); // 114.1 MB
    const size_t sc_bytes  = (size_t)B * 64u * sizeof(f32x2);         // 256 MB

    if (ws_size >= tab_bytes + sc_bytes) {
        f16x2* wtab = (f16x2*)d_ws;
        f32x2* sc   = (f32x2*)((char*)d_ws + tab_bytes);

        dim3 cgrid((TABLE_SIZE + 255u) / 256u, 4);
        convert_tables_kernel<<<cgrid, 256, 0, stream>>>(e0, e1, e2, e3, wtab);

        int nchunk = (B + 255) / 256;
        nchunk = (nchunk + 7) & ~7;              // %8==0 -> chunk->XCD striping
        hg_pass_kernel<<<64 * nchunk, 256, 0, stream>>>(x, t, wtab, sc, B, nchunk);

        transpose_kernel<<<(B + 63) / 64, 256, 0, stream>>>(sc, out, B);
    } else if (ws_size >= tab_bytes) {
        f16x2* wtab = (f16x2*)d_ws;
        dim3 cgrid((TABLE_SIZE + 255u) / 256u, 4);
        convert_tables_kernel<<<cgrid, 256, 0, stream>>>(e0, e1, e2, e3, wtab);
        const long long total = (long long)B * 64;
        const int blocks = (int)((total + 255) / 256);
        hashgrid4d_f16_kernel<<<blocks, 256, 0, stream>>>(x, t, wtab, out, B);
    }
    // (ws_size is always >= tab_bytes in this harness; minimal fallback omitted)
}

// Round 5
// 727.442 us; speedup vs baseline: 3.5818x; 1.2740x over previous
//
#include <hip/hip_runtime.h>

#define HASH_MASK ((1u << 19) - 1u)
#define TAB_STRIDE 7131228u            // padded entries per table (poff %4 == 0)
#define SCALE 1048576.0f               // 2^20 (exact)
#define INV_SCALE 9.5367431640625e-07f // 2^-20 (exact)

typedef float    f32x2 __attribute__((ext_vector_type(2)));
typedef _Float16 f16x2 __attribute__((ext_vector_type(2)));
typedef _Float16 f16x4v __attribute__((ext_vector_type(4)));
typedef _Float16 f16x8v __attribute__((ext_vector_type(8)));

// Original (reference) level offsets and sizes.
__device__ __forceinline__ unsigned orig_off(int l) {
    if (l >= 3) return 315475u + (unsigned)(l - 3) * 524288u;
    return (l == 0) ? 0u : ((l == 1) ? 4913u : 40850u);
}
__device__ __forceinline__ unsigned hsize(int l) {
    if (l >= 3) return 524288u;
    return (l == 0) ? 4913u : ((l == 1) ? 35937u : 274625u);
}
// Padded offsets: every slice starts on a 16B boundary (entry index %4==0).
__device__ __forceinline__ unsigned poff(int l) {
    if (l >= 3) return 315484u + (unsigned)(l - 3) * 524288u;
    return (l == 0) ? 0u : ((l == 1) ? 4916u : 40856u);
}

// ---------------- pre-pass: f32 tables -> fp16 (x 2^20), padded layout -------
__global__ __launch_bounds__(256) void convert_tables_kernel(
    const float* __restrict__ e0, const float* __restrict__ e1,
    const float* __restrict__ e2, const float* __restrict__ e3,
    f16x2* __restrict__ ws)
{
    const int l = (int)blockIdx.z;
    const unsigned hs = hsize(l);
    const unsigned i = blockIdx.x * 256u + threadIdx.x;
    if (i >= hs) return;
    const float* src = (blockIdx.y == 0) ? e0 : ((blockIdx.y == 1) ? e1
                     : ((blockIdx.y == 2) ? e2 : e3));
    const f32x2 v = __builtin_nontemporal_load(
        reinterpret_cast<const f32x2*>(src) + (orig_off(l) + i));
    f16x2 h;
    h.x = (_Float16)(v.x * SCALE);
    h.y = (_Float16)(v.y * SCALE);
    ws[blockIdx.y * TAB_STRIDE + poff(l) + i] = h;
}

// ------------- main pass: one (encode,level) combo per block ----------------
// blockIdx.x = combo * nchunk + chunk -> dispatch order serializes combos so
// the combo's <=2MB fp16 slice stays L2-resident on every XCD.
__global__ __launch_bounds__(256) void hg_pass_kernel(
    const float* __restrict__ x, const float* __restrict__ t,
    const f16x2* __restrict__ ws, f16x2* __restrict__ sc,
    int B, int nchunk)
{
    const int combo = blockIdx.x / nchunk;
    const int chunk = blockIdx.x - combo * nchunk;
    const int point = chunk * 256 + threadIdx.x;
    if (point >= B) return;
    const int e = combo >> 4;     // combo = e*16 + l
    const int l = combo & 15;

    const float x0 = x[point * 3 + 0];
    const float x1 = x[point * 3 + 1];
    const float x2 = x[point * 3 + 2];
    const float tt = t[point];
    // e0:(x0,x1,x2) e1:(x0,x1,t) e2:(x0,x2,t) e3:(x1,x2,t)
    const float c0 = (e == 3) ? x1 : x0;
    const float c1 = (e <= 1) ? x1 : x2;
    const float c2 = (e == 0) ? x2 : tt;

    const f16x2* __restrict__ tab = ws + (size_t)e * TAB_STRIDE + poff(l);

    const int res = 16 << l;
    const float resf = (float)res;
    const float p0 = c0 * resf, p1 = c1 * resf, p2 = c2 * resf;
    const float fl0 = floorf(p0), fl1 = floorf(p1), fl2 = floorf(p2);
    const float f0 = p0 - fl0, f1 = p1 - fl1, f2 = p2 - fl2;
    const unsigned g0 = (unsigned)min(max((int)fl0, 0), res - 1);
    const unsigned g1 = (unsigned)min(max((int)fl1, 0), res - 1);
    const unsigned g2 = (unsigned)min(max((int)fl2, 0), res - 1);

    const bool dense = (l < 3);
    const unsigned r1 = (unsigned)(res + 1);
    const unsigned r1sq = r1 * r1;
    const unsigned d_base = g0 + g1 * r1 + g2 * r1sq;
    const unsigned h1a = g1 * 2654435761u, h1b = (g1 + 1u) * 2654435761u;
    const unsigned h2a = g2 * 805459861u,  h2b = (g2 + 1u) * 805459861u;
    const float omf0 = 1.0f - f0, omf1 = 1.0f - f1, omf2 = 1.0f - f2;

    float a0 = 0.0f, a1 = 0.0f;
#pragma unroll
    for (int pr = 0; pr < 4; ++pr) {      // (by,bz) corner pairs; bx in {0,1}
        const int by = pr & 1, bz = pr >> 1;
        const float wyz = (by ? f1 : omf1) * (bz ? f2 : omf2);
        const float w0 = omf0 * wyz, w1 = f0 * wyz;
        unsigned u0, u1;
        if (dense) {
            const unsigned b = d_base + (by ? r1 : 0u) + (bz ? r1sq : 0u);
            u0 = b; u1 = b + 1u;
        } else {
            const unsigned H = (by ? h1b : h1a) ^ (bz ? h2b : h2a);
            u0 = (g0 ^ H) & HASH_MASK;
            u1 = ((g0 + 1u) ^ H) & HASH_MASK;
        }
        f16x2 v0, v1;
        if ((u0 ^ u1) < 4u) {
            // both corners in one aligned 16B quad: single dwordx4 gather
            const f16x8v q = *reinterpret_cast<const f16x8v*>(tab + (u0 & ~3u));
            f16x2 q0; q0.x = q[0]; q0.y = q[1];
            f16x2 q1; q1.x = q[2]; q1.y = q[3];
            f16x2 q2; q2.x = q[4]; q2.y = q[5];
            f16x2 q3; q3.x = q[6]; q3.y = q[7];
            const unsigned s0 = u0 & 3u, s1 = u1 & 3u;
            v0 = (s0 & 2u) ? ((s0 & 1u) ? q3 : q2) : ((s0 & 1u) ? q1 : q0);
            v1 = (s1 & 2u) ? ((s1 & 1u) ? q3 : q2) : ((s1 & 1u) ? q1 : q0);
        } else {
            v0 = tab[u0];
            v1 = tab[u1];
        }
        a0 = fmaf(w0, (float)v0.x, fmaf(w1, (float)v1.x, a0));
        a1 = fmaf(w0, (float)v0.y, fmaf(w1, (float)v1.y, a1));
    }

    // fp16 scratch (still scaled by 2^20), combo-major, coalesced 4B/lane.
    f16x2 r;
    r.x = (_Float16)a0;
    r.y = (_Float16)a1;
    __builtin_nontemporal_store(r, &sc[(size_t)combo * (size_t)B + (size_t)point]);
}

// ------------- transpose: sc[64 combos][B] (fp16) -> out[B][128] (f32) ------
__global__ __launch_bounds__(256) void transpose_kernel(
    const f16x2* __restrict__ sc, float* __restrict__ out, int B)
{
    __shared__ f16x2 tile[64][65];   // 65 pad: conflict-free both phases
    const int pbase = blockIdx.x * 64;
    const int tid = (int)threadIdx.x;

    const int prr = tid & 63;
    const int gp_r = pbase + prr;
#pragma unroll
    for (int i = 0; i < 16; ++i) {
        const int c = i * 4 + (tid >> 6);
        if (gp_r < B)
            tile[prr][c] = __builtin_nontemporal_load(&sc[(size_t)c * (size_t)B + (size_t)gp_r]);
    }
    __syncthreads();

    const int wv = tid >> 6;         // wave id 0..3
    const int ln = tid & 63;         // lane = combo
#pragma unroll
    for (int j = 0; j < 16; ++j) {
        const int p = wv * 16 + j;
        const int gp = pbase + p;
        if (gp < B) {
            const f16x2 v = tile[p][ln];
            f32x2 o;
            o.x = (float)v.x * INV_SCALE;
            o.y = (float)v.y * INV_SCALE;
            __builtin_nontemporal_store(o, reinterpret_cast<f32x2*>(out + (size_t)gp * 128 + ln * 2));
        }
    }
}

// ---------------- fallback: f32 fused (no workspace needed) -----------------
__global__ __launch_bounds__(256) void hashgrid4d_f32_kernel(
    const float* __restrict__ x, const float* __restrict__ t,
    const float* __restrict__ e0, const float* __restrict__ e1,
    const float* __restrict__ e2, const float* __restrict__ e3,
    float* __restrict__ out, int B)
{
    const int gid   = blockIdx.x * blockDim.x + threadIdx.x;
    const int point = gid >> 6;
    if (point >= B) return;
    const int lane = threadIdx.x & 63;
    const int l = lane & 15;
    const int e = lane >> 4;

    const float x0 = x[point * 3 + 0], x1 = x[point * 3 + 1], x2 = x[point * 3 + 2];
    const float tt = t[point];
    const float c0 = (e == 3) ? x1 : x0;
    const float c1 = (e <= 1) ? x1 : x2;
    const float c2 = (e == 0) ? x2 : tt;
    const float* tab = (e == 0) ? e0 : ((e == 1) ? e1 : ((e == 2) ? e2 : e3));

    const int res = 16 << l;
    const float resf = (float)res;
    const float p0 = c0 * resf, p1 = c1 * resf, p2 = c2 * resf;
    const float fl0 = floorf(p0), fl1 = floorf(p1), fl2 = floorf(p2);
    const float f0 = p0 - fl0, f1 = p1 - fl1, f2 = p2 - fl2;
    const unsigned g0 = (unsigned)min(max((int)fl0, 0), res - 1);
    const unsigned g1 = (unsigned)min(max((int)fl1, 0), res - 1);
    const unsigned g2 = (unsigned)min(max((int)fl2, 0), res - 1);
    const bool dense = (l < 3);
    const unsigned offs = orig_off(l);
    const unsigned r1 = (unsigned)(res + 1), r1sq = r1 * r1;
    const unsigned d_base = g0 + g1 * r1 + g2 * r1sq;
    const unsigned h1a = g1 * 2654435761u, h1b = (g1 + 1u) * 2654435761u;
    const unsigned h2a = g2 * 805459861u,  h2b = (g2 + 1u) * 805459861u;
    const float omf0 = 1.0f - f0, omf1 = 1.0f - f1, omf2 = 1.0f - f2;

    float a0 = 0.0f, a1 = 0.0f;
#pragma unroll
    for (int c = 0; c < 8; ++c) {
        const int bx = c & 1, by = (c >> 1) & 1, bz = c >> 2;
        const float w = (bx ? f0 : omf0) * (by ? f1 : omf1) * (bz ? f2 : omf2);
        const unsigned di = d_base + (bx ? 1u : 0u) + (by ? r1 : 0u) + (bz ? r1sq : 0u);
        const unsigned hi = (((g0 + (unsigned)bx) ^ (by ? h1b : h1a) ^ (bz ? h2b : h2a)) & HASH_MASK);
        const unsigned idx = dense ? di : hi;
        const f32x2 v = *reinterpret_cast<const f32x2*>(tab + 2u * (offs + idx));
        a0 = fmaf(w, v.x, a0);
        a1 = fmaf(w, v.y, a1);
    }
    f32x2 r; r.x = a0; r.y = a1;
    __builtin_nontemporal_store(r, reinterpret_cast<f32x2*>(out + (size_t)point * 128 + lane * 2));
}

extern "C" void kernel_launch(void* const* d_in, const int* in_sizes, int n_in,
                              void* d_out, int out_size, void* d_ws, size_t ws_size,
                              hipStream_t stream) {
    const float* x  = (const float*)d_in[0];
    const float* t  = (const float*)d_in[1];
    const float* e0 = (const float*)d_in[2];
    const float* e1 = (const float*)d_in[3];
    const float* e2 = (const float*)d_in[4];
    const float* e3 = (const float*)d_in[5];
    float* out = (float*)d_out;
    const int B = in_sizes[0] / 3;

    const size_t tab_bytes = (size_t)TAB_STRIDE * 4u * sizeof(f16x2); // 114.1 MB
    const size_t sc_bytes  = (size_t)B * 64u * sizeof(f16x2);         // 128 MB

    if (ws_size >= tab_bytes + sc_bytes) {
        f16x2* wtab = (f16x2*)d_ws;
        f16x2* sc   = (f16x2*)((char*)d_ws + tab_bytes);

        dim3 cgrid(2048, 4, 16);  // x: up to 524288 entries/level, y: table, z: level
        convert_tables_kernel<<<cgrid, 256, 0, stream>>>(e0, e1, e2, e3, wtab);

        int nchunk = (B + 255) / 256;
        nchunk = (nchunk + 7) & ~7;              // %8==0 -> chunk->XCD striping
        hg_pass_kernel<<<64 * nchunk, 256, 0, stream>>>(x, t, wtab, sc, B, nchunk);

        transpose_kernel<<<(B + 63) / 64, 256, 0, stream>>>(sc, out, B);
    } else {
        const long long total = (long long)B * 64;
        const int blocks = (int)((total + 255) / 256);
        hashgrid4d_f32_kernel<<<blocks, 256, 0, stream>>>(x, t, e0, e1, e2, e3, out, B);
    }
}